// Round 2
// baseline (556.317 us; speedup 1.0000x reference)
//
#include <hip/hip_runtime.h>
#include <math.h>

#define BS 4
#define NTOK 196
#define DCH 384
#define NHEAD 16
#define HD 6144
#define ROWS (BS*NTOK)          // 784
#define SCALE 0.05103103630798287f  // 1/sqrt(384)

// ---------------------------------------------------------------- LayerNorm
__global__ __launch_bounds__(128) void ln_kernel(
    const float* __restrict__ x, const float* __restrict__ gamma,
    const float* __restrict__ beta, float* __restrict__ xn)
{
    int row = blockIdx.x;
    int t = threadIdx.x;                // 128 threads, 2 waves
    const float* xr = x + (size_t)row * DCH;
    float v0 = xr[t], v1 = xr[t + 128], v2 = xr[t + 256];
    float s  = v0 + v1 + v2;
    float ss = v0*v0 + v1*v1 + v2*v2;
    #pragma unroll
    for (int off = 1; off < 64; off <<= 1) {
        s  += __shfl_xor(s,  off);
        ss += __shfl_xor(ss, off);
    }
    __shared__ float red[4];
    int wv = t >> 6;
    if ((t & 63) == 0) { red[wv*2] = s; red[wv*2+1] = ss; }
    __syncthreads();
    float S = red[0] + red[2], SS = red[1] + red[3];
    float mu  = S * (1.0f / DCH);
    float var = SS * (1.0f / DCH) - mu * mu;
    float inv = rsqrtf(var + 1e-5f);
    float* xo = xn + (size_t)row * DCH;
    xo[t]       = (v0 - mu) * inv * gamma[t]       + beta[t];
    xo[t + 128] = (v1 - mu) * inv * gamma[t + 128] + beta[t + 128];
    xo[t + 256] = (v2 - mu) * inv * gamma[t + 256] + beta[t + 256];
}

// ------------------------------------------------- projection GEMM (fused q/k/v)
// C[784,6144] = A[784,384] @ W[384,6144]; BM=64 BN=128 BK=16, 128 thr, 8x8 micro
__global__ __launch_bounds__(128) void gemm_proj_kernel(
    const float* __restrict__ A,
    const float* __restrict__ Wq, const float* __restrict__ Wk, const float* __restrict__ Wv,
    float* __restrict__ qo, float* __restrict__ ko, float* __restrict__ vo)
{
    const float* W = (blockIdx.z == 0) ? Wq : (blockIdx.z == 1) ? Wk : Wv;
    float* C       = (blockIdx.z == 0) ? qo : (blockIdx.z == 1) ? ko : vo;

    __shared__ float As[16][64];
    __shared__ float Bs[16][128];
    int tid = threadIdx.x;
    int tx = tid & 15, ty = tid >> 4;   // 16 x 8
    int row0 = blockIdx.y * 64;
    int col0 = blockIdx.x * 128;
    float acc[8][8] = {};

    int ar = tid >> 1, akq = (tid & 1) * 8;
    int bk = tid >> 3, bc = (tid & 7) * 16;

    for (int k0 = 0; k0 < 384; k0 += 16) {
        int row = row0 + ar;
        float4 a0, a1;
        if (row < ROWS) {
            a0 = *(const float4*)(A + (size_t)row*384 + k0 + akq);
            a1 = *(const float4*)(A + (size_t)row*384 + k0 + akq + 4);
        } else { a0 = float4{0,0,0,0}; a1 = a0; }
        const float* wr = W + (size_t)(k0 + bk) * HD + col0 + bc;
        float4 b0 = *(const float4*)(wr);
        float4 b1 = *(const float4*)(wr + 4);
        float4 b2 = *(const float4*)(wr + 8);
        float4 b3 = *(const float4*)(wr + 12);
        __syncthreads();
        As[akq+0][ar] = a0.x; As[akq+1][ar] = a0.y; As[akq+2][ar] = a0.z; As[akq+3][ar] = a0.w;
        As[akq+4][ar] = a1.x; As[akq+5][ar] = a1.y; As[akq+6][ar] = a1.z; As[akq+7][ar] = a1.w;
        *(float4*)&Bs[bk][bc]      = b0;
        *(float4*)&Bs[bk][bc + 4]  = b1;
        *(float4*)&Bs[bk][bc + 8]  = b2;
        *(float4*)&Bs[bk][bc + 12] = b3;
        __syncthreads();
        #pragma unroll
        for (int kk = 0; kk < 16; kk++) {
            float a[8], b[8];
            *(float4*)&a[0] = *(const float4*)&As[kk][ty*8];
            *(float4*)&a[4] = *(const float4*)&As[kk][ty*8 + 4];
            *(float4*)&b[0] = *(const float4*)&Bs[kk][tx*8];
            *(float4*)&b[4] = *(const float4*)&Bs[kk][tx*8 + 4];
            #pragma unroll
            for (int i = 0; i < 8; i++)
                #pragma unroll
                for (int j = 0; j < 8; j++)
                    acc[i][j] += a[i] * b[j];
        }
    }
    #pragma unroll
    for (int i = 0; i < 8; i++) {
        int row = row0 + ty*8 + i;
        if (row < ROWS) {
            float4 o0 = {acc[i][0], acc[i][1], acc[i][2], acc[i][3]};
            float4 o1 = {acc[i][4], acc[i][5], acc[i][6], acc[i][7]};
            *(float4*)(C + (size_t)row*HD + col0 + tx*8)     = o0;
            *(float4*)(C + (size_t)row*HD + col0 + tx*8 + 4) = o1;
        }
    }
}

// ------------------------------------------------- attention per (b, dc)
__global__ __launch_bounds__(256) void attn_kernel(
    const float* __restrict__ qb, const float* __restrict__ kb, const float* __restrict__ vb,
    float* __restrict__ probs, float* __restrict__ attnb)
{
    __shared__ float Qs[NTOK * 16];     // [i][h]
    __shared__ float Vs[NTOK * 16];     // [j][h]
    __shared__ float Pbuf[32 * 200];    // [i_local][j], stride 200 >= NTOK
    int bd = blockIdx.x;
    int b = bd / DCH, dc = bd - b * DCH;
    int tid = threadIdx.x;
    int lane = tid & 63, wv = tid >> 6;
    size_t base = (size_t)b * NTOK * HD + dc;

    for (int e = tid; e < NTOK * 16; e += 256) {
        int i = e >> 4, h = e & 15;
        size_t g = base + (size_t)i * HD + (size_t)h * DCH;
        Qs[e] = qb[g];
        Vs[e] = vb[g];
    }
    float Kreg[4][16];
    #pragma unroll
    for (int t = 0; t < 4; t++) {
        int j = t * 64 + lane;
        const float* kp = kb + base + (size_t)j * HD;
        #pragma unroll
        for (int h = 0; h < 16; h++)
            Kreg[t][h] = (j < NTOK) ? kp[(size_t)h * DCH] : 0.f;
    }
    __syncthreads();

    float* probs_bd = probs + (size_t)bd * NTOK * NTOK;

    for (int r0 = 0; r0 < NTOK; r0 += 32) {
        int nb = min(32, NTOK - r0);
        // ---- scores + softmax: wave handles rows r0+wv, r0+wv+4, ...
        for (int il = wv; il < nb; il += 4) {
            int i = r0 + il;
            float4 q0 = *(const float4*)&Qs[i*16];
            float4 q1 = *(const float4*)&Qs[i*16 + 4];
            float4 q2 = *(const float4*)&Qs[i*16 + 8];
            float4 q3 = *(const float4*)&Qs[i*16 + 12];
            float s[4];
            #pragma unroll
            for (int t = 0; t < 4; t++) {
                float a;
                a  = q0.x*Kreg[t][0]  + q0.y*Kreg[t][1]  + q0.z*Kreg[t][2]  + q0.w*Kreg[t][3];
                a += q1.x*Kreg[t][4]  + q1.y*Kreg[t][5]  + q1.z*Kreg[t][6]  + q1.w*Kreg[t][7];
                a += q2.x*Kreg[t][8]  + q2.y*Kreg[t][9]  + q2.z*Kreg[t][10] + q2.w*Kreg[t][11];
                a += q3.x*Kreg[t][12] + q3.y*Kreg[t][13] + q3.z*Kreg[t][14] + q3.w*Kreg[t][15];
                int j = t * 64 + lane;
                s[t] = (j < NTOK) ? a * SCALE : -INFINITY;
            }
            float m = fmaxf(fmaxf(s[0], s[1]), fmaxf(s[2], s[3]));
            #pragma unroll
            for (int off = 1; off < 64; off <<= 1) m = fmaxf(m, __shfl_xor(m, off));
            float p[4]; float sum = 0.f;
            #pragma unroll
            for (int t = 0; t < 4; t++) {
                int j = t * 64 + lane;
                p[t] = (j < NTOK) ? __expf(s[t] - m) : 0.f;
                sum += p[t];
            }
            #pragma unroll
            for (int off = 1; off < 64; off <<= 1) sum += __shfl_xor(sum, off);
            float inv = 1.0f / sum;
            float* prow = probs_bd + (size_t)i * NTOK;
            #pragma unroll
            for (int t = 0; t < 4; t++) {
                int j = t * 64 + lane;
                if (j < NTOK) {
                    float pv = p[t] * inv;
                    prow[j] = pv;
                    Pbuf[il * 200 + j] = pv;
                }
            }
        }
        __syncthreads();
        // ---- PV: wave covers 8 rows; lane = (itsub -> 2 rows, ht, jq)
        {
            int itsub = lane >> 4;          // 0..3
            int ht = (lane >> 2) & 3;       // 0..3
            int jq = lane & 3;              // 0..3
            int rowbase = wv * 8 + itsub * 2;
            bool active = rowbase < nb;
            float acc[2][4] = {{0.f,0.f,0.f,0.f},{0.f,0.f,0.f,0.f}};
            for (int ch = jq; ch < 49; ch += 4) {
                int j = ch * 4;
                if (active) {
                    float pr[2][4];
                    *(float4*)pr[0] = *(const float4*)&Pbuf[(rowbase+0)*200 + j];
                    *(float4*)pr[1] = *(const float4*)&Pbuf[(rowbase+1)*200 + j];
                    #pragma unroll
                    for (int js = 0; js < 4; js++) {
                        float4 vvv = *(const float4*)&Vs[(j+js)*16 + ht*4];
                        #pragma unroll
                        for (int r = 0; r < 2; r++) {
                            acc[r][0] += pr[r][js] * vvv.x;
                            acc[r][1] += pr[r][js] * vvv.y;
                            acc[r][2] += pr[r][js] * vvv.z;
                            acc[r][3] += pr[r][js] * vvv.w;
                        }
                    }
                }
            }
            #pragma unroll
            for (int r = 0; r < 2; r++)
                #pragma unroll
                for (int e = 0; e < 4; e++) {
                    float v2 = acc[r][e];
                    v2 += __shfl_xor(v2, 1);
                    v2 += __shfl_xor(v2, 2);
                    acc[r][e] = v2;
                }
            if (active && jq == 0) {
                #pragma unroll
                for (int r = 0; r < 2; r++) {
                    int i = r0 + rowbase + r;
                    size_t orow = base + (size_t)i * HD;
                    #pragma unroll
                    for (int e = 0; e < 4; e++)
                        attnb[orow + (size_t)(ht*4 + e) * DCH] = acc[r][e];
                }
            }
        }
        __syncthreads();
    }
}

// ------------------------------------------------- out projection, split-K
// partial[z][784,384] = attn[784, z*512:(z+1)*512] @ Wout[z*512:(z+1)*512, 384]
__global__ __launch_bounds__(128) void gemm_wout_kernel(
    const float* __restrict__ A, const float* __restrict__ W, float* __restrict__ partial)
{
    __shared__ float As[16][64];
    __shared__ float Bs[16][128];
    int tid = threadIdx.x;
    int tx = tid & 15, ty = tid >> 4;
    int row0 = blockIdx.y * 64;
    int col0 = blockIdx.x * 128;
    int kstart = blockIdx.z * 512;
    float acc[8][8] = {};

    int ar = tid >> 1, akq = (tid & 1) * 8;
    int bk = tid >> 3, bc = (tid & 7) * 16;

    for (int k0 = kstart; k0 < kstart + 512; k0 += 16) {
        int row = row0 + ar;
        float4 a0, a1;
        if (row < ROWS) {
            a0 = *(const float4*)(A + (size_t)row*HD + k0 + akq);
            a1 = *(const float4*)(A + (size_t)row*HD + k0 + akq + 4);
        } else { a0 = float4{0,0,0,0}; a1 = a0; }
        const float* wr = W + (size_t)(k0 + bk) * DCH + col0 + bc;
        float4 b0 = *(const float4*)(wr);
        float4 b1 = *(const float4*)(wr + 4);
        float4 b2 = *(const float4*)(wr + 8);
        float4 b3 = *(const float4*)(wr + 12);
        __syncthreads();
        As[akq+0][ar] = a0.x; As[akq+1][ar] = a0.y; As[akq+2][ar] = a0.z; As[akq+3][ar] = a0.w;
        As[akq+4][ar] = a1.x; As[akq+5][ar] = a1.y; As[akq+6][ar] = a1.z; As[akq+7][ar] = a1.w;
        *(float4*)&Bs[bk][bc]      = b0;
        *(float4*)&Bs[bk][bc + 4]  = b1;
        *(float4*)&Bs[bk][bc + 8]  = b2;
        *(float4*)&Bs[bk][bc + 12] = b3;
        __syncthreads();
        #pragma unroll
        for (int kk = 0; kk < 16; kk++) {
            float a[8], b[8];
            *(float4*)&a[0] = *(const float4*)&As[kk][ty*8];
            *(float4*)&a[4] = *(const float4*)&As[kk][ty*8 + 4];
            *(float4*)&b[0] = *(const float4*)&Bs[kk][tx*8];
            *(float4*)&b[4] = *(const float4*)&Bs[kk][tx*8 + 4];
            #pragma unroll
            for (int i = 0; i < 8; i++)
                #pragma unroll
                for (int j = 0; j < 8; j++)
                    acc[i][j] += a[i] * b[j];
        }
    }
    float* P = partial + (size_t)blockIdx.z * ROWS * DCH;
    #pragma unroll
    for (int i = 0; i < 8; i++) {
        int row = row0 + ty*8 + i;
        if (row < ROWS) {
            float4 o0 = {acc[i][0], acc[i][1], acc[i][2], acc[i][3]};
            float4 o1 = {acc[i][4], acc[i][5], acc[i][6], acc[i][7]};
            *(float4*)(P + (size_t)row*DCH + col0 + tx*8)     = o0;
            *(float4*)(P + (size_t)row*DCH + col0 + tx*8 + 4) = o1;
        }
    }
}

// ------------------------------------------------- split-K reduce + residual
__global__ __launch_bounds__(256) void reduce_out_kernel(
    const float* __restrict__ partial, const float* __restrict__ xn, float* __restrict__ out)
{
    int e = blockIdx.x * 256 + threadIdx.x;
    if (e < ROWS * DCH) {
        float s = xn[e];
        #pragma unroll
        for (int c = 0; c < 12; c++)
            s += partial[(size_t)c * ROWS * DCH + e];
        out[e] = s;
    }
}

extern "C" void kernel_launch(void* const* d_in, const int* in_sizes, int n_in,
                              void* d_out, int out_size, void* d_ws, size_t ws_size,
                              hipStream_t stream) {
    (void)in_sizes; (void)n_in; (void)out_size; (void)ws_size;
    const float* x     = (const float*)d_in[0];
    const float* Wq    = (const float*)d_in[1];
    const float* Wk    = (const float*)d_in[2];
    const float* Wv    = (const float*)d_in[3];
    const float* Wout  = (const float*)d_in[4];
    const float* gamma = (const float*)d_in[5];
    const float* beta  = (const float*)d_in[6];

    float* out   = (float*)d_out;                 // 784*384
    float* probs = out + (size_t)ROWS * DCH;      // 1536*196*196

    float* ws    = (float*)d_ws;
    float* xn    = ws;                                  // 301,056
    float* qb    = ws + (size_t)ROWS * DCH;             // 4,816,896
    float* kb    = qb + (size_t)ROWS * HD;
    float* vb    = kb + (size_t)ROWS * HD;
    float* attnb = qb;            // alias: block (b,dc) writes exactly the q elements it already consumed
    float* partial = kb;          // k no longer needed after attention; 12*301056 < 4,816,896

    hipLaunchKernelGGL(ln_kernel, dim3(ROWS), dim3(128), 0, stream, x, gamma, beta, xn);
    hipLaunchKernelGGL(gemm_proj_kernel, dim3(48, 13, 3), dim3(128), 0, stream,
                       xn, Wq, Wk, Wv, qb, kb, vb);
    hipLaunchKernelGGL(attn_kernel, dim3(BS * DCH), dim3(256), 0, stream,
                       qb, kb, vb, probs, attnb);
    hipLaunchKernelGGL(gemm_wout_kernel, dim3(3, 13, 12), dim3(128), 0, stream,
                       attnb, Wout, partial);
    hipLaunchKernelGGL(reduce_out_kernel, dim3((ROWS * DCH + 255) / 256), dim3(256), 0, stream,
                       partial, xn, out);
}

// Round 3
// 499.712 us; speedup vs baseline: 1.1133x; 1.1133x over previous
//
#include <hip/hip_runtime.h>
#include <math.h>

#define BS 4
#define NTOK 196
#define DCH 384
#define NHEAD 16
#define HD 6144
#define ROWS (BS*NTOK)          // 784
#define SCALE 0.05103103630798287f  // 1/sqrt(384)

// ---------------------------------------------------------------- LayerNorm
__global__ __launch_bounds__(128) void ln_kernel(
    const float* __restrict__ x, const float* __restrict__ gamma,
    const float* __restrict__ beta, float* __restrict__ xn)
{
    int row = blockIdx.x;
    int t = threadIdx.x;                // 128 threads, 2 waves
    const float* xr = x + (size_t)row * DCH;
    float v0 = xr[t], v1 = xr[t + 128], v2 = xr[t + 256];
    float s  = v0 + v1 + v2;
    float ss = v0*v0 + v1*v1 + v2*v2;
    #pragma unroll
    for (int off = 1; off < 64; off <<= 1) {
        s  += __shfl_xor(s,  off);
        ss += __shfl_xor(ss, off);
    }
    __shared__ float red[4];
    int wv = t >> 6;
    if ((t & 63) == 0) { red[wv*2] = s; red[wv*2+1] = ss; }
    __syncthreads();
    float S = red[0] + red[2], SS = red[1] + red[3];
    float mu  = S * (1.0f / DCH);
    float var = SS * (1.0f / DCH) - mu * mu;
    float inv = rsqrtf(var + 1e-5f);
    float* xo = xn + (size_t)row * DCH;
    xo[t]       = (v0 - mu) * inv * gamma[t]       + beta[t];
    xo[t + 128] = (v1 - mu) * inv * gamma[t + 128] + beta[t + 128];
    xo[t + 256] = (v2 - mu) * inv * gamma[t + 256] + beta[t + 256];
}

// ------------------------------------------------- projection GEMM (fused q/k/v)
// C[row=b*196+i][col=h*384+dc] = A[784,384] @ W[384,6144]
// written TRANSPOSED to q_t[((b*384+dc)*16+h)*196 + i]
__global__ __launch_bounds__(128) void gemm_proj_kernel(
    const float* __restrict__ A,
    const float* __restrict__ Wq, const float* __restrict__ Wk, const float* __restrict__ Wv,
    float* __restrict__ qo, float* __restrict__ ko, float* __restrict__ vo)
{
    const float* W = (blockIdx.z == 0) ? Wq : (blockIdx.z == 1) ? Wk : Wv;
    float* C       = (blockIdx.z == 0) ? qo : (blockIdx.z == 1) ? ko : vo;

    __shared__ float As[16][64];
    __shared__ float Bs[16][128];
    int tid = threadIdx.x;
    int tx = tid & 15, ty = tid >> 4;   // 16 x 8
    int row0 = blockIdx.y * 64;
    int col0 = blockIdx.x * 128;
    float acc[8][8] = {};

    int ar = tid >> 1, akq = (tid & 1) * 8;
    int bk = tid >> 3, bc = (tid & 7) * 16;

    for (int k0 = 0; k0 < 384; k0 += 16) {
        int row = row0 + ar;
        float4 a0, a1;
        if (row < ROWS) {
            a0 = *(const float4*)(A + (size_t)row*384 + k0 + akq);
            a1 = *(const float4*)(A + (size_t)row*384 + k0 + akq + 4);
        } else { a0 = float4{0,0,0,0}; a1 = a0; }
        const float* wr = W + (size_t)(k0 + bk) * HD + col0 + bc;
        float4 b0 = *(const float4*)(wr);
        float4 b1 = *(const float4*)(wr + 4);
        float4 b2 = *(const float4*)(wr + 8);
        float4 b3 = *(const float4*)(wr + 12);
        __syncthreads();
        As[akq+0][ar] = a0.x; As[akq+1][ar] = a0.y; As[akq+2][ar] = a0.z; As[akq+3][ar] = a0.w;
        As[akq+4][ar] = a1.x; As[akq+5][ar] = a1.y; As[akq+6][ar] = a1.z; As[akq+7][ar] = a1.w;
        *(float4*)&Bs[bk][bc]      = b0;
        *(float4*)&Bs[bk][bc + 4]  = b1;
        *(float4*)&Bs[bk][bc + 8]  = b2;
        *(float4*)&Bs[bk][bc + 12] = b3;
        __syncthreads();
        #pragma unroll
        for (int kk = 0; kk < 16; kk++) {
            float a[8], b[8];
            *(float4*)&a[0] = *(const float4*)&As[kk][ty*8];
            *(float4*)&a[4] = *(const float4*)&As[kk][ty*8 + 4];
            *(float4*)&b[0] = *(const float4*)&Bs[kk][tx*8];
            *(float4*)&b[4] = *(const float4*)&Bs[kk][tx*8 + 4];
            #pragma unroll
            for (int i = 0; i < 8; i++)
                #pragma unroll
                for (int j = 0; j < 8; j++)
                    acc[i][j] += a[i] * b[j];
        }
    }
    // transposed store: [(b*384+dc)*16+h][i], 4-row float4 groups (196%4==0 so
    // 4-aligned row groups never straddle the b boundary)
    int h = col0 / DCH;
    int dcbase = col0 % DCH;
    int ar0 = row0 + ty*8;
    if (ar0 < ROWS) {
        int b0 = ar0 / NTOK, i0 = ar0 - b0*NTOK;
        int ar1 = ar0 + 4;
        int b1 = ar1 / NTOK, i1 = ar1 - b1*NTOK;
        #pragma unroll
        for (int j = 0; j < 8; j++) {
            int dc = dcbase + tx*8 + j;
            float4 o0 = {acc[0][j], acc[1][j], acc[2][j], acc[3][j]};
            float4 o1 = {acc[4][j], acc[5][j], acc[6][j], acc[7][j]};
            *(float4*)(C + ((size_t)(b0*DCH + dc)*16 + h)*NTOK + i0) = o0;
            *(float4*)(C + ((size_t)(b1*DCH + dc)*16 + h)*NTOK + i1) = o1;
        }
    }
}

// ------------------------------------------------- attention per (b, dc)
// q_t/k_t/v_t layout: [bd][h][i] contiguous 3136 floats per bd.
// output ot aliases q_t (block writes exactly its own q region).
__global__ __launch_bounds__(256) void attn_kernel(
    const float* __restrict__ qt, const float* __restrict__ kt, const float* __restrict__ vt,
    float* __restrict__ probs, float* __restrict__ ot)
{
    __shared__ float Qs[NTOK * 20];      // [i][h], stride 20 (16B-aligned rows)
    __shared__ float Vs[16 * NTOK];      // [h][j]
    __shared__ float Pbuf[16 * NTOK];    // [il][j]
    int bd = blockIdx.x;
    int tid = threadIdx.x;
    int lane = tid & 63, wv = tid >> 6;
    size_t base = (size_t)bd * (NTOK * 16);

    // coalesced loads; Q transposed into [i][h]
    for (int e4 = tid; e4 < (NTOK*16)/4; e4 += 256) {
        int e = e4 * 4;
        float4 qv = *(const float4*)(qt + base + e);
        float4 vv = *(const float4*)(vt + base + e);
        *(float4*)&Vs[e] = vv;
        int h = e / NTOK;
        int i = e - h * NTOK;
        Qs[(i+0)*20 + h] = qv.x;
        Qs[(i+1)*20 + h] = qv.y;
        Qs[(i+2)*20 + h] = qv.z;
        Qs[(i+3)*20 + h] = qv.w;
    }
    // K in registers, coalesced
    float Kreg[4][16];
    #pragma unroll
    for (int t = 0; t < 4; t++) {
        int j = t * 64 + lane;
        #pragma unroll
        for (int h = 0; h < 16; h++)
            Kreg[t][h] = (j < NTOK) ? kt[base + h*NTOK + j] : 0.f;
    }
    __syncthreads();

    float* probs_bd = probs + (size_t)bd * NTOK * NTOK;

    for (int r0 = 0; r0 < NTOK; r0 += 16) {
        int nb = min(16, NTOK - r0);
        // ---- scores + softmax: wave handles batch-local rows wv, wv+4, ...
        for (int il = wv; il < nb; il += 4) {
            int i = r0 + il;
            float4 q0 = *(const float4*)&Qs[i*20];
            float4 q1 = *(const float4*)&Qs[i*20 + 4];
            float4 q2 = *(const float4*)&Qs[i*20 + 8];
            float4 q3 = *(const float4*)&Qs[i*20 + 12];
            float s[4];
            #pragma unroll
            for (int t = 0; t < 4; t++) {
                float a;
                a  = q0.x*Kreg[t][0]  + q0.y*Kreg[t][1]  + q0.z*Kreg[t][2]  + q0.w*Kreg[t][3];
                a += q1.x*Kreg[t][4]  + q1.y*Kreg[t][5]  + q1.z*Kreg[t][6]  + q1.w*Kreg[t][7];
                a += q2.x*Kreg[t][8]  + q2.y*Kreg[t][9]  + q2.z*Kreg[t][10] + q2.w*Kreg[t][11];
                a += q3.x*Kreg[t][12] + q3.y*Kreg[t][13] + q3.z*Kreg[t][14] + q3.w*Kreg[t][15];
                int j = t * 64 + lane;
                s[t] = (j < NTOK) ? a * SCALE : -INFINITY;
            }
            float m = fmaxf(fmaxf(s[0], s[1]), fmaxf(s[2], s[3]));
            #pragma unroll
            for (int off = 1; off < 64; off <<= 1) m = fmaxf(m, __shfl_xor(m, off));
            float p[4]; float sum = 0.f;
            #pragma unroll
            for (int t = 0; t < 4; t++) {
                int j = t * 64 + lane;
                p[t] = (j < NTOK) ? __expf(s[t] - m) : 0.f;
                sum += p[t];
            }
            #pragma unroll
            for (int off = 1; off < 64; off <<= 1) sum += __shfl_xor(sum, off);
            float inv = 1.0f / sum;
            float* prow = probs_bd + (size_t)i * NTOK;
            #pragma unroll
            for (int t = 0; t < 4; t++) {
                int j = t * 64 + lane;
                if (j < NTOK) {
                    float pv = p[t] * inv;
                    prow[j] = pv;
                    Pbuf[il * NTOK + j] = pv;
                }
            }
        }
        __syncthreads();
        // ---- PV: wave wv owns batch rows wv*4..wv*4+3; lane = (h, jq)
        {
            int hq = lane >> 2;          // h = 0..15
            int jq = lane & 3;
            int rowbase = wv * 4;
            bool active = rowbase < nb;
            float acc0 = 0.f, acc1 = 0.f, acc2 = 0.f, acc3 = 0.f;
            if (active) {
                const float* Vrow = &Vs[hq * NTOK];
                for (int ch = jq; ch < 49; ch += 4) {
                    int j0 = ch * 4;
                    float4 vv = *(const float4*)&Vrow[j0];
                    float4 p0 = *(const float4*)&Pbuf[(rowbase+0)*NTOK + j0];
                    float4 p1 = *(const float4*)&Pbuf[(rowbase+1)*NTOK + j0];
                    float4 p2 = *(const float4*)&Pbuf[(rowbase+2)*NTOK + j0];
                    float4 p3 = *(const float4*)&Pbuf[(rowbase+3)*NTOK + j0];
                    acc0 += p0.x*vv.x + p0.y*vv.y + p0.z*vv.z + p0.w*vv.w;
                    acc1 += p1.x*vv.x + p1.y*vv.y + p1.z*vv.z + p1.w*vv.w;
                    acc2 += p2.x*vv.x + p2.y*vv.y + p2.z*vv.z + p2.w*vv.w;
                    acc3 += p3.x*vv.x + p3.y*vv.y + p3.z*vv.z + p3.w*vv.w;
                }
            }
            #pragma unroll
            for (int off = 1; off < 4; off <<= 1) {
                acc0 += __shfl_xor(acc0, off);
                acc1 += __shfl_xor(acc1, off);
                acc2 += __shfl_xor(acc2, off);
                acc3 += __shfl_xor(acc3, off);
            }
            if (active && jq == 0) {
                float4 o = {acc0, acc1, acc2, acc3};
                *(float4*)(ot + base + (size_t)hq * NTOK + r0 + rowbase) = o;
            }
        }
        __syncthreads();
    }
}

// ------------------------------------------------- out projection, split-K
// C[b*196+i][col] = sum_{k''} ot[(b*6144+k'')*196+i] * Wout[(k''%16)*384 + k''/16][col]
__global__ __launch_bounds__(128) void gemm_wout_kernel(
    const float* __restrict__ A, const float* __restrict__ W, float* __restrict__ partial)
{
    __shared__ float As[16][68];
    __shared__ float Bs[16][128];
    int tid = threadIdx.x;
    int tx = tid & 15, ty = tid >> 4;
    int bb = blockIdx.y >> 2;            // batch b
    int i0 = (blockIdx.y & 3) * 64;      // i tile
    int col0 = blockIdx.x * 128;
    int kstart = blockIdx.z * 512;
    float acc[8][8] = {};

    int kl = tid >> 3, io = (tid & 7) * 8;
    int bk = tid >> 3, bc = (tid & 7) * 16;

    for (int k0 = kstart; k0 < kstart + 512; k0 += 16) {
        // A-tile: k-major, contiguous in i
        const float* Ab = A + ((size_t)bb * HD + k0 + kl) * NTOK + i0 + io;
        float4 a0 = (i0 + io + 3 < NTOK) ? *(const float4*)(Ab)     : float4{0,0,0,0};
        float4 a1 = (i0 + io + 7 < NTOK) ? *(const float4*)(Ab + 4) : float4{0,0,0,0};
        // B-tile: permuted Wout row
        int kpp = k0 + bk;
        int worig = (kpp & 15) * DCH + (kpp >> 4);
        const float* wr = W + (size_t)worig * DCH + col0 + bc;
        float4 b0 = *(const float4*)(wr);
        float4 b1 = *(const float4*)(wr + 4);
        float4 b2 = *(const float4*)(wr + 8);
        float4 b3 = *(const float4*)(wr + 12);
        __syncthreads();
        *(float4*)&As[kl][io]     = a0;
        *(float4*)&As[kl][io + 4] = a1;
        *(float4*)&Bs[bk][bc]      = b0;
        *(float4*)&Bs[bk][bc + 4]  = b1;
        *(float4*)&Bs[bk][bc + 8]  = b2;
        *(float4*)&Bs[bk][bc + 12] = b3;
        __syncthreads();
        #pragma unroll
        for (int kk = 0; kk < 16; kk++) {
            float a[8], b[8];
            *(float4*)&a[0] = *(const float4*)&As[kk][ty*8];
            *(float4*)&a[4] = *(const float4*)&As[kk][ty*8 + 4];
            *(float4*)&b[0] = *(const float4*)&Bs[kk][tx*8];
            *(float4*)&b[4] = *(const float4*)&Bs[kk][tx*8 + 4];
            #pragma unroll
            for (int i = 0; i < 8; i++)
                #pragma unroll
                for (int j = 0; j < 8; j++)
                    acc[i][j] += a[i] * b[j];
        }
    }
    float* P = partial + (size_t)blockIdx.z * ROWS * DCH;
    #pragma unroll
    for (int i = 0; i < 8; i++) {
        int ii = i0 + ty*8 + i;
        if (ii < NTOK) {
            int row = bb * NTOK + ii;
            float4 o0 = {acc[i][0], acc[i][1], acc[i][2], acc[i][3]};
            float4 o1 = {acc[i][4], acc[i][5], acc[i][6], acc[i][7]};
            *(float4*)(P + (size_t)row*DCH + col0 + tx*8)     = o0;
            *(float4*)(P + (size_t)row*DCH + col0 + tx*8 + 4) = o1;
        }
    }
}

// ------------------------------------------------- split-K reduce + residual
__global__ __launch_bounds__(256) void reduce_out_kernel(
    const float* __restrict__ partial, const float* __restrict__ xn, float* __restrict__ out)
{
    int e = blockIdx.x * 256 + threadIdx.x;
    if (e < ROWS * DCH) {
        float s = xn[e];
        #pragma unroll
        for (int c = 0; c < 12; c++)
            s += partial[(size_t)c * ROWS * DCH + e];
        out[e] = s;
    }
}

extern "C" void kernel_launch(void* const* d_in, const int* in_sizes, int n_in,
                              void* d_out, int out_size, void* d_ws, size_t ws_size,
                              hipStream_t stream) {
    (void)in_sizes; (void)n_in; (void)out_size; (void)ws_size;
    const float* x     = (const float*)d_in[0];
    const float* Wq    = (const float*)d_in[1];
    const float* Wk    = (const float*)d_in[2];
    const float* Wv    = (const float*)d_in[3];
    const float* Wout  = (const float*)d_in[4];
    const float* gamma = (const float*)d_in[5];
    const float* beta  = (const float*)d_in[6];

    float* out   = (float*)d_out;                 // 784*384
    float* probs = out + (size_t)ROWS * DCH;      // 1536*196*196

    float* ws    = (float*)d_ws;
    float* xn    = ws;                                  // 301,056
    float* qt    = ws + (size_t)ROWS * DCH;             // 4,816,896 each
    float* kt    = qt + (size_t)ROWS * HD;
    float* vt    = kt + (size_t)ROWS * HD;
    float* ot    = qt;            // alias: block bd writes exactly its own q region
    float* partial = kt;          // k dead after attention; 12*301056 < 4,816,896

    hipLaunchKernelGGL(ln_kernel, dim3(ROWS), dim3(128), 0, stream, x, gamma, beta, xn);
    hipLaunchKernelGGL(gemm_proj_kernel, dim3(48, 13, 3), dim3(128), 0, stream,
                       xn, Wq, Wk, Wv, qt, kt, vt);
    hipLaunchKernelGGL(attn_kernel, dim3(BS * DCH), dim3(256), 0, stream,
                       qt, kt, vt, probs, ot);
    hipLaunchKernelGGL(gemm_wout_kernel, dim3(3, 16, 12), dim3(128), 0, stream,
                       ot, Wout, partial);
    hipLaunchKernelGGL(reduce_out_kernel, dim3((ROWS * DCH + 255) / 256), dim3(256), 0, stream,
                       partial, xn, out);
}

// Round 4
// 230.151 us; speedup vs baseline: 2.4172x; 2.1712x over previous
//
#include <hip/hip_runtime.h>
#include <math.h>

#define BS 4
#define NTOK 196
#define DCH 384
#define HD 6144
#define ROWS (BS*NTOK)          // 784
#define MPAD 896                // 7*128
#define SCALE 0.05103103630798287f  // 1/sqrt(384)

typedef unsigned short u16;
typedef __attribute__((ext_vector_type(8))) short bf8v;      // 8 bf16 (4 VGPR)
typedef __attribute__((ext_vector_type(4))) float f4v;       // MFMA acc
typedef __attribute__((ext_vector_type(8))) unsigned short u16x8;
typedef __attribute__((ext_vector_type(4))) unsigned short u16x4;

static __device__ __forceinline__ float b2f(u16 u) {
    unsigned int x = ((unsigned int)u) << 16;
    float f; __builtin_memcpy(&f, &x, 4); return f;
}
static __device__ __forceinline__ u16 f2b(float f) {
    unsigned int x; __builtin_memcpy(&x, &f, 4);
    unsigned int r = x + 0x7FFF + ((x >> 16) & 1);
    return (u16)(r >> 16);
}

// ---------------------------------------------------------------- LayerNorm (f32 + bf16 out, pad to 896)
__global__ __launch_bounds__(128) void ln_kernel(
    const float* __restrict__ x, const float* __restrict__ gamma,
    const float* __restrict__ beta, float* __restrict__ xn, u16* __restrict__ xnb)
{
    int row = blockIdx.x;
    int t = threadIdx.x;
    if (row >= ROWS) {   // zero pad rows for MFMA A-tiles
        xnb[(size_t)row*DCH + t] = 0;
        xnb[(size_t)row*DCH + t + 128] = 0;
        xnb[(size_t)row*DCH + t + 256] = 0;
        return;
    }
    const float* xr = x + (size_t)row * DCH;
    float v0 = xr[t], v1 = xr[t + 128], v2 = xr[t + 256];
    float s  = v0 + v1 + v2;
    float ss = v0*v0 + v1*v1 + v2*v2;
    #pragma unroll
    for (int off = 1; off < 64; off <<= 1) {
        s  += __shfl_xor(s,  off);
        ss += __shfl_xor(ss, off);
    }
    __shared__ float red[4];
    int wv = t >> 6;
    if ((t & 63) == 0) { red[wv*2] = s; red[wv*2+1] = ss; }
    __syncthreads();
    float S = red[0] + red[2], SS = red[1] + red[3];
    float mu  = S * (1.0f / DCH);
    float var = SS * (1.0f / DCH) - mu * mu;
    float inv = rsqrtf(var + 1e-5f);
    float* xo = xn + (size_t)row * DCH;
    u16*   xb = xnb + (size_t)row * DCH;
    float r0 = (v0 - mu) * inv * gamma[t]       + beta[t];
    float r1 = (v1 - mu) * inv * gamma[t + 128] + beta[t + 128];
    float r2 = (v2 - mu) * inv * gamma[t + 256] + beta[t + 256];
    xo[t] = r0; xo[t+128] = r1; xo[t+256] = r2;
    xb[t] = f2b(r0); xb[t+128] = f2b(r1); xb[t+256] = f2b(r2);
}

// ------------------------------------------------- W[384][6144] -> Wb[n][k] bf16 (k-contiguous)
__global__ __launch_bounds__(256) void convert_w_kernel(
    const float* __restrict__ Wq, const float* __restrict__ Wk, const float* __restrict__ Wv,
    u16* __restrict__ Wqb, u16* __restrict__ Wkb, u16* __restrict__ Wvb)
{
    const float* W = (blockIdx.z == 0) ? Wq : (blockIdx.z == 1) ? Wk : Wv;
    u16* Wb        = (blockIdx.z == 0) ? Wqb : (blockIdx.z == 1) ? Wkb : Wvb;
    __shared__ u16 tbuf[32][33];
    int tid = threadIdx.x;
    int k0 = blockIdx.y * 32, n0 = blockIdx.x * 32;
    #pragma unroll
    for (int it = 0; it < 4; it++) {
        int e = it*256 + tid; int kk = e >> 5, nn = e & 31;
        tbuf[kk][nn] = f2b(W[(size_t)(k0+kk)*HD + n0 + nn]);
    }
    __syncthreads();
    #pragma unroll
    for (int it = 0; it < 4; it++) {
        int e = it*256 + tid; int nn = e >> 5, kk = e & 31;
        Wb[(size_t)(n0+nn)*DCH + k0 + kk] = tbuf[kk][nn];
    }
}

// ------------------------------------------------- Wout[6144][384] -> Woutb[n][k] bf16, k=dc*16+h, row perm folded
__global__ __launch_bounds__(256) void convert_wout_kernel(
    const float* __restrict__ Wout, u16* __restrict__ Woutb)
{
    __shared__ u16 tbuf[128][65];
    int tid = threadIdx.x;
    int dc0 = blockIdx.x * 8;      // 48 blocks
    int n0  = blockIdx.y * 64;     // 6 blocks
    #pragma unroll
    for (int it = 0; it < 32; it++) {
        int e = it*256 + tid; int r = e >> 6, c = e & 63;
        int h = r >> 3, d = r & 7;
        tbuf[r][c] = f2b(Wout[(size_t)(h*DCH + dc0 + d)*DCH + n0 + c]);
    }
    __syncthreads();
    #pragma unroll
    for (int it = 0; it < 32; it++) {
        int e = it*256 + tid; int n = e >> 7, kk = e & 127;
        Woutb[(size_t)(n0+n)*HD + dc0*16 + kk] = tbuf[(kk & 15)*8 + (kk >> 4)][n];
    }
}

// ------------------------------------------------- MFMA proj GEMM: [896x384]@[384x6144] -> q/k/v bf16 [b,dc,h][i]
__global__ __launch_bounds__(256) void gemm_qkv(
    const u16* __restrict__ xnb,
    const u16* __restrict__ Wqb, const u16* __restrict__ Wkb, const u16* __restrict__ Wvb,
    u16* __restrict__ qt, u16* __restrict__ kt, u16* __restrict__ vt)
{
    const u16* Wb = (blockIdx.z == 0) ? Wqb : (blockIdx.z == 1) ? Wkb : Wvb;
    u16* C        = (blockIdx.z == 0) ? qt : (blockIdx.z == 1) ? kt : vt;
    __shared__ u16 As[128*64];
    __shared__ u16 Bs[128*64];
    int tid = threadIdx.x, lane = tid & 63, wv = tid >> 6;
    int wm = wv >> 1, wn = wv & 1;
    int row0 = blockIdx.y * 128, col0 = blockIdx.x * 128;
    f4v acc[4][4] = {};
    int rsub = tid >> 3;            // 0..31
    int g8 = tid & 7;
    int g8s = g8 ^ (rsub & 7);      // XOR-swizzled chunk slot (row&7 const across c)

    for (int k0 = 0; k0 < 384; k0 += 64) {
        u16x8 ra[4], rb[4];
        #pragma unroll
        for (int c = 0; c < 4; c++) {
            int row = c*32 + rsub;
            ra[c] = *(const u16x8*)(xnb + (size_t)(row0+row)*DCH + k0 + g8*8);
            rb[c] = *(const u16x8*)(Wb  + (size_t)(col0+row)*DCH + k0 + g8*8);
        }
        __syncthreads();
        #pragma unroll
        for (int c = 0; c < 4; c++) {
            int row = c*32 + rsub;
            *(u16x8*)&As[row*64 + g8s*8] = ra[c];
            *(u16x8*)&Bs[row*64 + g8s*8] = rb[c];
        }
        __syncthreads();
        #pragma unroll
        for (int ks = 0; ks < 2; ks++) {
            int gr = (ks*4 + (lane >> 4)) ^ (lane & 7);
            bf8v af[4], bf[4];
            #pragma unroll
            for (int m = 0; m < 4; m++)
                af[m] = *(const bf8v*)&As[(wm*64 + m*16 + (lane & 15))*64 + gr*8];
            #pragma unroll
            for (int n = 0; n < 4; n++)
                bf[n] = *(const bf8v*)&Bs[(wn*64 + n*16 + (lane & 15))*64 + gr*8];
            #pragma unroll
            for (int m = 0; m < 4; m++)
                #pragma unroll
                for (int n = 0; n < 4; n++)
                    acc[m][n] = __builtin_amdgcn_mfma_f32_16x16x32_bf16(af[m], bf[n], acc[m][n], 0, 0, 0);
        }
    }
    int cb = lane & 15, rg = lane >> 4;
    #pragma unroll
    for (int m = 0; m < 4; m++) {
        int r0 = row0 + wm*64 + m*16 + rg*4;
        if (r0 >= ROWS) continue;
        int b = r0 / NTOK, i = r0 - b*NTOK;    // 4-row group never straddles b (196%4==0)
        #pragma unroll
        for (int n = 0; n < 4; n++) {
            int ncol = col0 + wn*64 + n*16 + cb;
            int h = ncol / DCH, dc = ncol - h*DCH;
            size_t addr = ((size_t)((b*DCH + dc)*16 + h))*NTOK + i;
            u16x4 o = {f2b(acc[m][n][0]), f2b(acc[m][n][1]), f2b(acc[m][n][2]), f2b(acc[m][n][3])};
            *(u16x4*)(C + addr) = o;
        }
    }
}

// ------------------------------------------------- attention per (b, dc); bf16 in, probs f32, out bf16 [b,i][dc*16+h]
__global__ __launch_bounds__(256) void attn_kernel(
    const u16* __restrict__ qt, const u16* __restrict__ kt, const u16* __restrict__ vt,
    float* __restrict__ probs, u16* __restrict__ ot2)
{
    __shared__ float Qs[NTOK * 20];      // [i][h]
    __shared__ float Vs[16 * NTOK];      // [h][j]
    __shared__ float Pbuf[16 * NTOK];    // [il][j]
    int bd = blockIdx.x;
    int b = bd / DCH, dc = bd - b*DCH;
    int tid = threadIdx.x;
    int lane = tid & 63, wv = tid >> 6;
    size_t base = (size_t)bd * (NTOK * 16);

    for (int e8 = tid; e8 < (NTOK*16)/8; e8 += 256) {
        u16x8 qv = *(const u16x8*)(qt + base + e8*8);
        u16x8 vv = *(const u16x8*)(vt + base + e8*8);
        #pragma unroll
        for (int j = 0; j < 8; j++) {
            int idx = e8*8 + j;
            int h = idx / NTOK, i = idx - h*NTOK;
            Vs[idx] = b2f(vv[j]);
            Qs[i*20 + h] = b2f(qv[j]);
        }
    }
    float Kreg[4][16];
    #pragma unroll
    for (int t = 0; t < 4; t++) {
        int j = t*64 + lane;
        #pragma unroll
        for (int h = 0; h < 16; h++)
            Kreg[t][h] = (j < NTOK) ? b2f(kt[base + h*NTOK + j]) : 0.f;
    }
    __syncthreads();

    float* probs_bd = probs + (size_t)bd * NTOK * NTOK;

    for (int r0 = 0; r0 < NTOK; r0 += 16) {
        int nb = min(16, NTOK - r0);
        for (int il = wv; il < nb; il += 4) {
            int i = r0 + il;
            float4 q0 = *(const float4*)&Qs[i*20];
            float4 q1 = *(const float4*)&Qs[i*20 + 4];
            float4 q2 = *(const float4*)&Qs[i*20 + 8];
            float4 q3 = *(const float4*)&Qs[i*20 + 12];
            float s[4];
            #pragma unroll
            for (int t = 0; t < 4; t++) {
                float a;
                a  = q0.x*Kreg[t][0]  + q0.y*Kreg[t][1]  + q0.z*Kreg[t][2]  + q0.w*Kreg[t][3];
                a += q1.x*Kreg[t][4]  + q1.y*Kreg[t][5]  + q1.z*Kreg[t][6]  + q1.w*Kreg[t][7];
                a += q2.x*Kreg[t][8]  + q2.y*Kreg[t][9]  + q2.z*Kreg[t][10] + q2.w*Kreg[t][11];
                a += q3.x*Kreg[t][12] + q3.y*Kreg[t][13] + q3.z*Kreg[t][14] + q3.w*Kreg[t][15];
                int j = t*64 + lane;
                s[t] = (j < NTOK) ? a * SCALE : -INFINITY;
            }
            float m = fmaxf(fmaxf(s[0], s[1]), fmaxf(s[2], s[3]));
            #pragma unroll
            for (int off = 1; off < 64; off <<= 1) m = fmaxf(m, __shfl_xor(m, off));
            float p[4]; float sum = 0.f;
            #pragma unroll
            for (int t = 0; t < 4; t++) {
                int j = t*64 + lane;
                p[t] = (j < NTOK) ? __expf(s[t] - m) : 0.f;
                sum += p[t];
            }
            #pragma unroll
            for (int off = 1; off < 64; off <<= 1) sum += __shfl_xor(sum, off);
            float inv = 1.0f / sum;
            float* prow = probs_bd + (size_t)i * NTOK;
            #pragma unroll
            for (int t = 0; t < 4; t++) {
                int j = t*64 + lane;
                if (j < NTOK) {
                    float pv = p[t] * inv;
                    prow[j] = pv;
                    Pbuf[il*NTOK + j] = pv;
                }
            }
        }
        __syncthreads();
        {
            int hq = lane >> 2;
            int jq = lane & 3;
            int rowbase = wv * 4;
            bool active = rowbase < nb;
            float acc0 = 0.f, acc1 = 0.f, acc2 = 0.f, acc3 = 0.f;
            if (active) {
                const float* Vrow = &Vs[hq * NTOK];
                for (int ch = jq; ch < 49; ch += 4) {
                    int j0 = ch * 4;
                    float4 vvv = *(const float4*)&Vrow[j0];
                    float4 p0 = *(const float4*)&Pbuf[(rowbase+0)*NTOK + j0];
                    float4 p1 = *(const float4*)&Pbuf[(rowbase+1)*NTOK + j0];
                    float4 p2 = *(const float4*)&Pbuf[(rowbase+2)*NTOK + j0];
                    float4 p3 = *(const float4*)&Pbuf[(rowbase+3)*NTOK + j0];
                    acc0 += p0.x*vvv.x + p0.y*vvv.y + p0.z*vvv.z + p0.w*vvv.w;
                    acc1 += p1.x*vvv.x + p1.y*vvv.y + p1.z*vvv.z + p1.w*vvv.w;
                    acc2 += p2.x*vvv.x + p2.y*vvv.y + p2.z*vvv.z + p2.w*vvv.w;
                    acc3 += p3.x*vvv.x + p3.y*vvv.y + p3.z*vvv.z + p3.w*vvv.w;
                }
            }
            #pragma unroll
            for (int off = 1; off < 4; off <<= 1) {
                acc0 += __shfl_xor(acc0, off);
                acc1 += __shfl_xor(acc1, off);
                acc2 += __shfl_xor(acc2, off);
                acc3 += __shfl_xor(acc3, off);
            }
            if (active && jq == 0) {
                int i0 = r0 + rowbase;
                size_t orow = ((size_t)(b*NTOK + i0)) * HD + dc*16 + hq;
                ot2[orow]        = f2b(acc0);
                ot2[orow + HD]   = f2b(acc1);
                ot2[orow + 2*HD] = f2b(acc2);
                ot2[orow + 3*HD] = f2b(acc3);
            }
        }
        __syncthreads();
    }
}

// ------------------------------------------------- MFMA out-proj, split-K: ot2[784x6144] @ Woutb^T -> partial
__global__ __launch_bounds__(256) void gemm_wout(
    const u16* __restrict__ A, const u16* __restrict__ Bw, float* __restrict__ partial)
{
    __shared__ u16 As[128*64];
    __shared__ u16 Bs[128*64];
    int tid = threadIdx.x, lane = tid & 63, wv = tid >> 6;
    int wm = wv >> 1, wn = wv & 1;
    int row0 = blockIdx.y * 128, col0 = blockIdx.x * 128;
    int kbase = blockIdx.z * 512;
    f4v acc[4][4] = {};
    int rsub = tid >> 3;
    int g8 = tid & 7;
    int g8s = g8 ^ (rsub & 7);

    for (int k0 = kbase; k0 < kbase + 512; k0 += 64) {
        u16x8 ra[4], rb[4];
        #pragma unroll
        for (int c = 0; c < 4; c++) {
            int row = c*32 + rsub;
            int arow = row0 + row; if (arow > ROWS-1) arow = ROWS-1;   // clamp (masked at store)
            ra[c] = *(const u16x8*)(A  + (size_t)arow*HD + k0 + g8*8);
            rb[c] = *(const u16x8*)(Bw + (size_t)(col0+row)*HD + k0 + g8*8);
        }
        __syncthreads();
        #pragma unroll
        for (int c = 0; c < 4; c++) {
            int row = c*32 + rsub;
            *(u16x8*)&As[row*64 + g8s*8] = ra[c];
            *(u16x8*)&Bs[row*64 + g8s*8] = rb[c];
        }
        __syncthreads();
        #pragma unroll
        for (int ks = 0; ks < 2; ks++) {
            int gr = (ks*4 + (lane >> 4)) ^ (lane & 7);
            bf8v af[4], bf[4];
            #pragma unroll
            for (int m = 0; m < 4; m++)
                af[m] = *(const bf8v*)&As[(wm*64 + m*16 + (lane & 15))*64 + gr*8];
            #pragma unroll
            for (int n = 0; n < 4; n++)
                bf[n] = *(const bf8v*)&Bs[(wn*64 + n*16 + (lane & 15))*64 + gr*8];
            #pragma unroll
            for (int m = 0; m < 4; m++)
                #pragma unroll
                for (int n = 0; n < 4; n++)
                    acc[m][n] = __builtin_amdgcn_mfma_f32_16x16x32_bf16(af[m], bf[n], acc[m][n], 0, 0, 0);
        }
    }
    float* P = partial + (size_t)blockIdx.z * ROWS * DCH;
    int cb = lane & 15, rg = lane >> 4;
    #pragma unroll
    for (int m = 0; m < 4; m++) {
        int r0 = row0 + wm*64 + m*16 + rg*4;
        #pragma unroll
        for (int n = 0; n < 4; n++) {
            int ncol = col0 + wn*64 + n*16 + cb;
            #pragma unroll
            for (int j = 0; j < 4; j++) {
                int r = r0 + j;
                if (r < ROWS) P[(size_t)r*DCH + ncol] = acc[m][n][j];
            }
        }
    }
}

// ------------------------------------------------- split-K reduce + residual
__global__ __launch_bounds__(256) void reduce_out_kernel(
    const float* __restrict__ partial, const float* __restrict__ xn, float* __restrict__ out)
{
    int e = blockIdx.x * 256 + threadIdx.x;
    if (e < ROWS * DCH) {
        float s = xn[e];
        #pragma unroll
        for (int c = 0; c < 12; c++)
            s += partial[(size_t)c * ROWS * DCH + e];
        out[e] = s;
    }
}

extern "C" void kernel_launch(void* const* d_in, const int* in_sizes, int n_in,
                              void* d_out, int out_size, void* d_ws, size_t ws_size,
                              hipStream_t stream) {
    (void)in_sizes; (void)n_in; (void)out_size; (void)ws_size;
    const float* x     = (const float*)d_in[0];
    const float* Wq    = (const float*)d_in[1];
    const float* Wk    = (const float*)d_in[2];
    const float* Wv    = (const float*)d_in[3];
    const float* Wout  = (const float*)d_in[4];
    const float* gamma = (const float*)d_in[5];
    const float* beta  = (const float*)d_in[6];

    float* out   = (float*)d_out;
    float* probs = out + (size_t)ROWS * DCH;

    char* w = (char*)d_ws;
    float* xn  = (float*)w;  w += (size_t)ROWS*DCH*4;        // 1,204,224
    u16* xnb   = (u16*)w;    w += (size_t)MPAD*DCH*2;        //   688,128
    u16* Wqb   = (u16*)w;    w += (size_t)HD*DCH*2;          // 4,718,592
    u16* Wkb   = (u16*)w;    w += (size_t)HD*DCH*2;
    u16* Wvb   = (u16*)w;    w += (size_t)HD*DCH*2;
    u16* Woutb = (u16*)w;    w += (size_t)DCH*HD*2;
    u16* qt    = (u16*)w;    w += (size_t)ROWS*HD*2;         // 9,633,792 each
    u16* kt    = (u16*)w;    w += (size_t)ROWS*HD*2;
    u16* vt    = (u16*)w;    w += (size_t)ROWS*HD*2;
    u16* ot2   = (u16*)w;    w += (size_t)ROWS*HD*2;
    float* partial = (float*)qt;   // 14.45 MB spans qt+kt, both dead after attention

    hipLaunchKernelGGL(ln_kernel, dim3(MPAD), dim3(128), 0, stream, x, gamma, beta, xn, xnb);
    hipLaunchKernelGGL(convert_w_kernel, dim3(192, 12, 3), dim3(256), 0, stream,
                       Wq, Wk, Wv, Wqb, Wkb, Wvb);
    hipLaunchKernelGGL(convert_wout_kernel, dim3(48, 6), dim3(256), 0, stream, Wout, Woutb);
    hipLaunchKernelGGL(gemm_qkv, dim3(48, 7, 3), dim3(256), 0, stream,
                       xnb, Wqb, Wkb, Wvb, qt, kt, vt);
    hipLaunchKernelGGL(attn_kernel, dim3(BS * DCH), dim3(256), 0, stream,
                       qt, kt, vt, probs, ot2);
    hipLaunchKernelGGL(gemm_wout, dim3(3, 7, 12), dim3(256), 0, stream, ot2, Woutb, partial);
    hipLaunchKernelGGL(reduce_out_kernel, dim3((ROWS * DCH + 255) / 256), dim3(256), 0, stream,
                       partial, xn, out);
}

// Round 5
// 195.120 us; speedup vs baseline: 2.8511x; 1.1795x over previous
//
#include <hip/hip_runtime.h>
#include <math.h>

#define BS 4
#define NTOK 196
#define DCH 384
#define HD 6144
#define ROWS (BS*NTOK)          // 784
#define MPAD 896                // 7*128
#define SCALE 0.05103103630798287f  // 1/sqrt(384)

typedef unsigned short u16;
typedef __attribute__((ext_vector_type(8))) short bf8v;      // 8 bf16 (4 VGPR)
typedef __attribute__((ext_vector_type(4))) float f4v;
typedef __attribute__((ext_vector_type(16))) float f16v;
typedef __attribute__((ext_vector_type(8))) unsigned short u16x8;
typedef __attribute__((ext_vector_type(4))) unsigned short u16x4;

static __device__ __forceinline__ float b2f(u16 u) {
    unsigned int x = ((unsigned int)u) << 16;
    float f; __builtin_memcpy(&f, &x, 4); return f;
}
static __device__ __forceinline__ u16 f2b(float f) {
    unsigned int x; __builtin_memcpy(&x, &f, 4);
    unsigned int r = x + 0x7FFF + ((x >> 16) & 1);
    return (u16)(r >> 16);
}

// ---------------------------------------------------------------- LayerNorm (f32 + bf16 out, pad to 896)
__global__ __launch_bounds__(128) void ln_kernel(
    const float* __restrict__ x, const float* __restrict__ gamma,
    const float* __restrict__ beta, float* __restrict__ xn, u16* __restrict__ xnb)
{
    int row = blockIdx.x;
    int t = threadIdx.x;
    if (row >= ROWS) {
        xnb[(size_t)row*DCH + t] = 0;
        xnb[(size_t)row*DCH + t + 128] = 0;
        xnb[(size_t)row*DCH + t + 256] = 0;
        return;
    }
    const float* xr = x + (size_t)row * DCH;
    float v0 = xr[t], v1 = xr[t + 128], v2 = xr[t + 256];
    float s  = v0 + v1 + v2;
    float ss = v0*v0 + v1*v1 + v2*v2;
    #pragma unroll
    for (int off = 1; off < 64; off <<= 1) {
        s  += __shfl_xor(s,  off);
        ss += __shfl_xor(ss, off);
    }
    __shared__ float red[4];
    int wv = t >> 6;
    if ((t & 63) == 0) { red[wv*2] = s; red[wv*2+1] = ss; }
    __syncthreads();
    float S = red[0] + red[2], SS = red[1] + red[3];
    float mu  = S * (1.0f / DCH);
    float var = SS * (1.0f / DCH) - mu * mu;
    float inv = rsqrtf(var + 1e-5f);
    float* xo = xn + (size_t)row * DCH;
    u16*   xb = xnb + (size_t)row * DCH;
    float r0 = (v0 - mu) * inv * gamma[t]       + beta[t];
    float r1 = (v1 - mu) * inv * gamma[t + 128] + beta[t + 128];
    float r2 = (v2 - mu) * inv * gamma[t + 256] + beta[t + 256];
    xo[t] = r0; xo[t+128] = r1; xo[t+256] = r2;
    xb[t] = f2b(r0); xb[t+128] = f2b(r1); xb[t+256] = f2b(r2);
}

// ------------------------------------------------- W[384][6144] -> Wb[n][k] bf16 (k-contiguous)
__global__ __launch_bounds__(256) void convert_w_kernel(
    const float* __restrict__ Wq, const float* __restrict__ Wk, const float* __restrict__ Wv,
    u16* __restrict__ Wqb, u16* __restrict__ Wkb, u16* __restrict__ Wvb)
{
    const float* W = (blockIdx.z == 0) ? Wq : (blockIdx.z == 1) ? Wk : Wv;
    u16* Wb        = (blockIdx.z == 0) ? Wqb : (blockIdx.z == 1) ? Wkb : Wvb;
    __shared__ u16 tbuf[32][33];
    int tid = threadIdx.x;
    int k0 = blockIdx.y * 32, n0 = blockIdx.x * 32;
    #pragma unroll
    for (int it = 0; it < 4; it++) {
        int e = it*256 + tid; int kk = e >> 5, nn = e & 31;
        tbuf[kk][nn] = f2b(W[(size_t)(k0+kk)*HD + n0 + nn]);
    }
    __syncthreads();
    #pragma unroll
    for (int it = 0; it < 4; it++) {
        int e = it*256 + tid; int nn = e >> 5, kk = e & 31;
        Wb[(size_t)(n0+nn)*DCH + k0 + kk] = tbuf[kk][nn];
    }
}

// ------------------------------------------------- Wout[6144][384] -> Woutb[n][k] bf16, k=dc*16+h
__global__ __launch_bounds__(256) void convert_wout_kernel(
    const float* __restrict__ Wout, u16* __restrict__ Woutb)
{
    __shared__ u16 tbuf[128][65];
    int tid = threadIdx.x;
    int dc0 = blockIdx.x * 8;
    int n0  = blockIdx.y * 64;
    #pragma unroll
    for (int it = 0; it < 32; it++) {
        int e = it*256 + tid; int r = e >> 6, c = e & 63;
        int h = r >> 3, d = r & 7;
        tbuf[r][c] = f2b(Wout[(size_t)(h*DCH + dc0 + d)*DCH + n0 + c]);
    }
    __syncthreads();
    #pragma unroll
    for (int it = 0; it < 32; it++) {
        int e = it*256 + tid; int n = e >> 7, kk = e & 127;
        Woutb[(size_t)(n0+n)*HD + dc0*16 + kk] = tbuf[(kk & 15)*8 + (kk >> 4)][n];
    }
}

// ------------------------------------------------- MFMA proj GEMM -> q/k [bd][i][h], v [bd][h][j]
__global__ __launch_bounds__(256) void gemm_qkv(
    const u16* __restrict__ xnb,
    const u16* __restrict__ Wqb, const u16* __restrict__ Wkb, const u16* __restrict__ Wvb,
    u16* __restrict__ qt, u16* __restrict__ kt, u16* __restrict__ vt)
{
    const u16* Wb = (blockIdx.z == 0) ? Wqb : (blockIdx.z == 1) ? Wkb : Wvb;
    u16* C        = (blockIdx.z == 0) ? qt : (blockIdx.z == 1) ? kt : vt;
    __shared__ u16 As[128*64];
    __shared__ u16 Bs[128*64];
    int tid = threadIdx.x, lane = tid & 63, wv = tid >> 6;
    int wm = wv >> 1, wn = wv & 1;
    int row0 = blockIdx.y * 128, col0 = blockIdx.x * 128;
    f4v acc[4][4] = {};
    int rsub = tid >> 3;
    int g8 = tid & 7;
    int g8s = g8 ^ (rsub & 7);

    for (int k0 = 0; k0 < 384; k0 += 64) {
        u16x8 ra[4], rb[4];
        #pragma unroll
        for (int c = 0; c < 4; c++) {
            int row = c*32 + rsub;
            ra[c] = *(const u16x8*)(xnb + (size_t)(row0+row)*DCH + k0 + g8*8);
            rb[c] = *(const u16x8*)(Wb  + (size_t)(col0+row)*DCH + k0 + g8*8);
        }
        __syncthreads();
        #pragma unroll
        for (int c = 0; c < 4; c++) {
            int row = c*32 + rsub;
            *(u16x8*)&As[row*64 + g8s*8] = ra[c];
            *(u16x8*)&Bs[row*64 + g8s*8] = rb[c];
        }
        __syncthreads();
        #pragma unroll
        for (int ks = 0; ks < 2; ks++) {
            int gr = (ks*4 + (lane >> 4)) ^ (lane & 7);
            bf8v af[4], bf[4];
            #pragma unroll
            for (int m = 0; m < 4; m++)
                af[m] = *(const bf8v*)&As[(wm*64 + m*16 + (lane & 15))*64 + gr*8];
            #pragma unroll
            for (int n = 0; n < 4; n++)
                bf[n] = *(const bf8v*)&Bs[(wn*64 + n*16 + (lane & 15))*64 + gr*8];
            #pragma unroll
            for (int m = 0; m < 4; m++)
                #pragma unroll
                for (int n = 0; n < 4; n++)
                    acc[m][n] = __builtin_amdgcn_mfma_f32_16x16x32_bf16(af[m], bf[n], acc[m][n], 0, 0, 0);
        }
    }
    int cb = lane & 15, rg = lane >> 4;
    #pragma unroll
    for (int m = 0; m < 4; m++) {
        int r0 = row0 + wm*64 + m*16 + rg*4;
        if (r0 >= ROWS) continue;
        int b = r0 / NTOK, i = r0 - b*NTOK;
        #pragma unroll
        for (int n = 0; n < 4; n++) {
            int ncol = col0 + wn*64 + n*16 + cb;
            int h = ncol / DCH, dc = ncol - h*DCH;
            if (blockIdx.z == 2) {
                size_t addr = ((size_t)((b*DCH + dc)*16 + h))*NTOK + i;
                u16x4 o = {f2b(acc[m][n][0]), f2b(acc[m][n][1]), f2b(acc[m][n][2]), f2b(acc[m][n][3])};
                *(u16x4*)(C + addr) = o;
            } else {
                size_t a2 = ((size_t)(b*DCH + dc))*(NTOK*16) + (size_t)i*16 + h;
                C[a2]      = f2b(acc[m][n][0]);
                C[a2 + 16] = f2b(acc[m][n][1]);
                C[a2 + 32] = f2b(acc[m][n][2]);
                C[a2 + 48] = f2b(acc[m][n][3]);
            }
        }
    }
}

// ------------------------------------------------- MFMA attention: block = bd, wave = 32-row i-tile
// q/k: [bd][i][h] bf16; v: [bd][h][j] bf16; probs f32; out bf16 [b,i][dc*16+h]
__global__ __launch_bounds__(448) void attn_kernel(
    const u16* __restrict__ qt, const u16* __restrict__ kt, const u16* __restrict__ vt,
    float* __restrict__ probs, u16* __restrict__ ot2)
{
    int bd = blockIdx.x;
    int b = bd / DCH, dc = bd - b*DCH;
    int tid = threadIdx.x;
    int it = tid >> 6;                 // 0..6 (wave = i-tile)
    int lane = tid & 63;
    int l31 = lane & 31, hi = lane >> 5;
    const u16* qb = qt + (size_t)bd * (NTOK*16);
    const u16* kb = kt + (size_t)bd * (NTOK*16);
    const u16* vb = vt + (size_t)bd * (NTOK*16);

    // Q fragment (B operand): col i = it*32+l31, k = h = hi*8+e
    int iq = it*32 + l31;
    int iqc = iq < NTOK ? iq : NTOK-1;
    bf8v qf = *(const bf8v*)(qb + iqc*16 + hi*8);

    // QK^T swapped: S[jt] = K_jt @ Q  (row=j, col=i)
    f16v S[7];
    #pragma unroll
    for (int jt = 0; jt < 7; jt++) {
        int j = jt*32 + l31;
        int jc = j < NTOK ? j : NTOK-1;
        bf8v kf = *(const bf8v*)(kb + jc*16 + hi*8);
        f16v z = {};
        S[jt] = __builtin_amdgcn_mfma_f32_32x32x16_bf16(kf, qf, z, 0, 0, 0);
    }

    // row softmax (lane-local + partner): j(jt,r) = 32jt + 8(r>>2) + 4hi + (r&3)
    float m = -INFINITY;
    #pragma unroll
    for (int jt = 0; jt < 7; jt++) {
        #pragma unroll
        for (int r = 0; r < 16; r++) {
            bool act = (jt < 6) || (hi == 0 && r < 4);
            if (act) m = fmaxf(m, S[jt][r]);
        }
    }
    m = fmaxf(m, __shfl_xor(m, 32));
    m *= SCALE;
    float sum = 0.f;
    #pragma unroll
    for (int jt = 0; jt < 7; jt++) {
        #pragma unroll
        for (int r = 0; r < 16; r++) {
            bool act = (jt < 6) || (hi == 0 && r < 4);
            float pv = act ? __expf(S[jt][r] * SCALE - m) : 0.f;
            S[jt][r] = pv;
            sum += pv;
        }
    }
    sum += __shfl_xor(sum, 32);
    float inv = 1.0f / sum;
    #pragma unroll
    for (int jt = 0; jt < 7; jt++)
        #pragma unroll
        for (int r = 0; r < 16; r++)
            S[jt][r] *= inv;

    // write probs rows (float4 per reg-quad)
    if (iq < NTOK) {
        float* prow = probs + (size_t)bd * NTOK * NTOK + (size_t)iq * NTOK;
        #pragma unroll
        for (int jt = 0; jt < 7; jt++) {
            #pragma unroll
            for (int g = 0; g < 4; g++) {
                int joff = jt*32 + g*8 + hi*4;
                if (joff < NTOK) {
                    float4 o = {S[jt][4*g], S[jt][4*g+1], S[jt][4*g+2], S[jt][4*g+3]};
                    *(float4*)(prow + joff) = o;
                }
            }
        }
    }

    // PV: O[i][h'] += P_frag(jt,u) @ V_frag(jt,u); A row = i = l31
    f16v O = {};
    int vrow = (l31 & 15) * NTOK;
    #pragma unroll
    for (int jt = 0; jt < 7; jt++) {
        float pp_lo[4], pp_hi[4];
        #pragma unroll
        for (int e = 0; e < 4; e++) {
            pp_lo[e] = __shfl_xor(hi ? S[jt][e]    : S[jt][4+e],  32);
            pp_hi[e] = __shfl_xor(hi ? S[jt][8+e]  : S[jt][12+e], 32);
        }
        #pragma unroll
        for (int u = 0; u < 2; u++) {
            if (jt == 6 && u == 1) break;   // all-zero P
            u16 arr[8];
            #pragma unroll
            for (int e = 0; e < 4; e++) {
                float s03, s47;
                if (u == 0) {
                    s03 = hi ? pp_lo[e]     : S[jt][e];
                    s47 = hi ? S[jt][4+e]   : pp_lo[e];
                } else {
                    s03 = hi ? pp_hi[e]     : S[jt][8+e];
                    s47 = hi ? S[jt][12+e]  : pp_hi[e];
                }
                arr[e]   = f2b(s03);
                arr[4+e] = f2b(s47);
            }
            bf8v pf; __builtin_memcpy(&pf, arr, 16);
            int j0 = jt*32 + u*16 + hi*8;
            int off = vrow + j0;
            if (off > NTOK*16 - 8) off = NTOK*16 - 8;   // clamp (P=0 there)
            u16x4 vlo = *(const u16x4*)(vb + off);
            u16x4 vhi4 = *(const u16x4*)(vb + off + 4);
            u16 varr[8];
            #pragma unroll
            for (int e = 0; e < 4; e++) { varr[e] = vlo[e]; varr[4+e] = vhi4[e]; }
            bf8v vf; __builtin_memcpy(&vf, varr, 16);
            O = __builtin_amdgcn_mfma_f32_32x32x16_bf16(pf, vf, O, 0, 0, 0);
        }
    }

    // store: D row = i_local = (r&3)+8*(r>>2)+4*hi, col = h' = l31 (only <16)
    if (l31 < 16) {
        #pragma unroll
        for (int r = 0; r < 16; r++) {
            int i = it*32 + (r & 3) + 8*(r >> 2) + 4*hi;
            if (i < NTOK)
                ot2[((size_t)(b*NTOK + i))*HD + dc*16 + l31] = f2b(O[r]);
        }
    }
}

// ------------------------------------------------- MFMA out-proj, split-K
__global__ __launch_bounds__(256) void gemm_wout(
    const u16* __restrict__ A, const u16* __restrict__ Bw, float* __restrict__ partial)
{
    __shared__ u16 As[128*64];
    __shared__ u16 Bs[128*64];
    int tid = threadIdx.x, lane = tid & 63, wv = tid >> 6;
    int wm = wv >> 1, wn = wv & 1;
    int row0 = blockIdx.y * 128, col0 = blockIdx.x * 128;
    int kbase = blockIdx.z * 512;
    f4v acc[4][4] = {};
    int rsub = tid >> 3;
    int g8 = tid & 7;
    int g8s = g8 ^ (rsub & 7);

    for (int k0 = kbase; k0 < kbase + 512; k0 += 64) {
        u16x8 ra[4], rb[4];
        #pragma unroll
        for (int c = 0; c < 4; c++) {
            int row = c*32 + rsub;
            int arow = row0 + row; if (arow > ROWS-1) arow = ROWS-1;
            ra[c] = *(const u16x8*)(A  + (size_t)arow*HD + k0 + g8*8);
            rb[c] = *(const u16x8*)(Bw + (size_t)(col0+row)*HD + k0 + g8*8);
        }
        __syncthreads();
        #pragma unroll
        for (int c = 0; c < 4; c++) {
            int row = c*32 + rsub;
            *(u16x8*)&As[row*64 + g8s*8] = ra[c];
            *(u16x8*)&Bs[row*64 + g8s*8] = rb[c];
        }
        __syncthreads();
        #pragma unroll
        for (int ks = 0; ks < 2; ks++) {
            int gr = (ks*4 + (lane >> 4)) ^ (lane & 7);
            bf8v af[4], bf[4];
            #pragma unroll
            for (int m = 0; m < 4; m++)
                af[m] = *(const bf8v*)&As[(wm*64 + m*16 + (lane & 15))*64 + gr*8];
            #pragma unroll
            for (int n = 0; n < 4; n++)
                bf[n] = *(const bf8v*)&Bs[(wn*64 + n*16 + (lane & 15))*64 + gr*8];
            #pragma unroll
            for (int m = 0; m < 4; m++)
                #pragma unroll
                for (int n = 0; n < 4; n++)
                    acc[m][n] = __builtin_amdgcn_mfma_f32_16x16x32_bf16(af[m], bf[n], acc[m][n], 0, 0, 0);
        }
    }
    float* P = partial + (size_t)blockIdx.z * ROWS * DCH;
    int cb = lane & 15, rg = lane >> 4;
    #pragma unroll
    for (int m = 0; m < 4; m++) {
        int r0 = row0 + wm*64 + m*16 + rg*4;
        #pragma unroll
        for (int n = 0; n < 4; n++) {
            int ncol = col0 + wn*64 + n*16 + cb;
            #pragma unroll
            for (int j = 0; j < 4; j++) {
                int r = r0 + j;
                if (r < ROWS) P[(size_t)r*DCH + ncol] = acc[m][n][j];
            }
        }
    }
}

// ------------------------------------------------- split-K reduce + residual
__global__ __launch_bounds__(256) void reduce_out_kernel(
    const float* __restrict__ partial, const float* __restrict__ xn, float* __restrict__ out)
{
    int e = blockIdx.x * 256 + threadIdx.x;
    if (e < ROWS * DCH) {
        float s = xn[e];
        #pragma unroll
        for (int c = 0; c < 12; c++)
            s += partial[(size_t)c * ROWS * DCH + e];
        out[e] = s;
    }
}

extern "C" void kernel_launch(void* const* d_in, const int* in_sizes, int n_in,
                              void* d_out, int out_size, void* d_ws, size_t ws_size,
                              hipStream_t stream) {
    (void)in_sizes; (void)n_in; (void)out_size; (void)ws_size;
    const float* x     = (const float*)d_in[0];
    const float* Wq    = (const float*)d_in[1];
    const float* Wk    = (const float*)d_in[2];
    const float* Wv    = (const float*)d_in[3];
    const float* Wout  = (const float*)d_in[4];
    const float* gamma = (const float*)d_in[5];
    const float* beta  = (const float*)d_in[6];

    float* out   = (float*)d_out;
    float* probs = out + (size_t)ROWS * DCH;

    char* w = (char*)d_ws;
    float* xn  = (float*)w;  w += (size_t)ROWS*DCH*4;
    u16* xnb   = (u16*)w;    w += (size_t)MPAD*DCH*2;
    u16* Wqb   = (u16*)w;    w += (size_t)HD*DCH*2;
    u16* Wkb   = (u16*)w;    w += (size_t)HD*DCH*2;
    u16* Wvb   = (u16*)w;    w += (size_t)HD*DCH*2;
    u16* Woutb = (u16*)w;    w += (size_t)DCH*HD*2;
    u16* qt    = (u16*)w;    w += (size_t)ROWS*HD*2;
    u16* kt    = (u16*)w;    w += (size_t)ROWS*HD*2;
    u16* vt    = (u16*)w;    w += (size_t)ROWS*HD*2;
    u16* ot2   = (u16*)w;    w += (size_t)ROWS*HD*2;
    float* partial = (float*)qt;   // q/k dead after attention

    hipLaunchKernelGGL(ln_kernel, dim3(MPAD), dim3(128), 0, stream, x, gamma, beta, xn, xnb);
    hipLaunchKernelGGL(convert_w_kernel, dim3(192, 12, 3), dim3(256), 0, stream,
                       Wq, Wk, Wv, Wqb, Wkb, Wvb);
    hipLaunchKernelGGL(convert_wout_kernel, dim3(48, 6), dim3(256), 0, stream, Wout, Woutb);
    hipLaunchKernelGGL(gemm_qkv, dim3(48, 7, 3), dim3(256), 0, stream,
                       xnb, Wqb, Wkb, Wvb, qt, kt, vt);
    hipLaunchKernelGGL(attn_kernel, dim3(BS * DCH), dim3(448), 0, stream,
                       qt, kt, vt, probs, ot2);
    hipLaunchKernelGGL(gemm_wout, dim3(3, 7, 12), dim3(256), 0, stream, ot2, Woutb, partial);
    hipLaunchKernelGGL(reduce_out_kernel, dim3((ROWS * DCH + 255) / 256), dim3(256), 0, stream,
                       partial, xn, out);
}